// Round 17
// baseline (675.605 us; speedup 1.0000x reference)
//
#include <hip/hip_runtime.h>

#define SEQ 4096
#define HID 512
#define NB  4
#define N3  1536
#define LOG2E 1.4426950408889634f

typedef _Float16 half_t;
typedef __attribute__((ext_vector_type(8))) _Float16 half8;
typedef __attribute__((ext_vector_type(4))) float f32x4;

#define GLOAD_LDS16(gp, lp) __builtin_amdgcn_global_load_lds((gp), (lp), 16, 0, 0)

#define LGKM_BARRIER()                                                       \
  asm volatile("s_waitcnt lgkmcnt(0)" ::: "memory");                         \
  __builtin_amdgcn_sched_barrier(0);                                         \
  __builtin_amdgcn_s_barrier();

// ---------------- convert x (f32) -> f16 ----------------
__global__ void k_cvt(const float* __restrict__ x, half_t* __restrict__ xh, int n4) {
  int i = blockIdx.x * blockDim.x + threadIdx.x;
  int stride = gridDim.x * blockDim.x;
  for (; i < n4; i += stride) {
    float4 v = reinterpret_cast<const float4*>(x)[i];
    union { half_t h[4]; short4 s; } u;
    u.h[0] = (half_t)v.x; u.h[1] = (half_t)v.y;
    u.h[2] = (half_t)v.z; u.h[3] = (half_t)v.w;
    reinterpret_cast<short4*>(xh)[i] = u.s;
  }
}

// ---------------- W [512][1536] f32 -> Wt [1536][512] f16 ----------------
__global__ void k_tw(const float* __restrict__ W, half_t* __restrict__ Wt) {
  __shared__ half_t tile[64][65];
  const int n0 = blockIdx.x * 64;
  const int k0 = blockIdx.y * 64;
  const int tx = threadIdx.x & 63, ty = threadIdx.x >> 6;
#pragma unroll
  for (int i = 0; i < 64; i += 4)
    tile[ty + i][tx] = (half_t)W[(size_t)(k0 + ty + i) * N3 + n0 + tx];
  __syncthreads();
#pragma unroll
  for (int i = 0; i < 64; i += 4)
    Wt[(size_t)(n0 + ty + i) * HID + k0 + tx] = tile[tx][ty + i];
}

// ---------------- QKV projection GEMM (V written fragment-packed) ----------------
__launch_bounds__(256)
__global__ void k_qkv(const half_t* __restrict__ xh, const half_t* __restrict__ Wt,
                      const float* __restrict__ bias,
                      half_t* __restrict__ Qh, half_t* __restrict__ Kh,
                      half_t* __restrict__ Vf) {
  __shared__ half_t sA[128 * 32];
  __shared__ half_t sB[128 * 32];
  const int t = threadIdx.x;
  const int m0 = blockIdx.y * 128;
  const int n0 = blockIdx.x * 128;
  const int lane = t & 63, wid = t >> 6;
  const int wr = (wid >> 1) * 64, wc = (wid & 1) * 64;
  const int lrow = lane & 15, lks = lane >> 4;
  const int s1 = t, s2 = t + 256;
  const int ar1 = s1 >> 2, ac1 = (s1 & 3) * 8;
  const int ar2 = s2 >> 2, ac2 = (s2 & 3) * 8;

  f32x4 acc[4][4] = {};

  for (int k0 = 0; k0 < HID; k0 += 32) {
    __syncthreads();
    GLOAD_LDS16(xh + (size_t)(m0 + ar1) * HID + k0 + ac1, &sA[s1 * 8]);
    GLOAD_LDS16(xh + (size_t)(m0 + ar2) * HID + k0 + ac2, &sA[s2 * 8]);
    GLOAD_LDS16(Wt + (size_t)(n0 + ar1) * HID + k0 + ac1, &sB[s1 * 8]);
    GLOAD_LDS16(Wt + (size_t)(n0 + ar2) * HID + k0 + ac2, &sB[s2 * 8]);
    __syncthreads();
    half8 a[4], b[4];
#pragma unroll
    for (int m = 0; m < 4; ++m)
      a[m] = *reinterpret_cast<const half8*>(&sA[(wr + m * 16 + lrow) * 32 + lks * 8]);
#pragma unroll
    for (int n = 0; n < 4; ++n)
      b[n] = *reinterpret_cast<const half8*>(&sB[(wc + n * 16 + lrow) * 32 + lks * 8]);
#pragma unroll
    for (int m = 0; m < 4; ++m)
#pragma unroll
      for (int n = 0; n < 4; ++n)
        acc[m][n] = __builtin_amdgcn_mfma_f32_16x16x32_f16(a[m], b[n], acc[m][n], 0, 0, 0);
  }

  const float scale = 0.04419417382415922f;  // 1/sqrt(512)
  const int region = n0 >> 9;  // 0=Q, 1=K, 2=V (uniform per block)
#pragma unroll
  for (int m = 0; m < 4; ++m) {
#pragma unroll
    for (int n = 0; n < 4; ++n) {
      const int col = n0 + wc + n * 16 + lrow;
#pragma unroll
      for (int r = 0; r < 4; ++r) {
        const int row = m0 + wr + m * 16 + lks * 4 + r;
        float v = acc[m][n][r] + bias[col];
        if (region == 0) {
          Qh[(size_t)row * HID + col] = (half_t)(v * scale);
        } else if (region == 1) {
          Kh[(size_t)row * HID + (col - 512)] = (half_t)v;
        } else {
          const int bb = row >> 12, s = row & (SEQ - 1), h = col - 1024;
          const int tl = bb * 4096 + (s >> 5) * 32 + (h >> 4);
          Vf[(size_t)tl * 512 + (((h & 15) | (((s >> 3) & 3) << 4)) * 8) + (s & 7)] =
              (half_t)v;
        }
      }
    }
  }
}

// ---------------- scores = Q @ K^T -> f16 Sh (ws, row-major) + partials ----------
__launch_bounds__(256)
__global__ void k_qk(const half_t* __restrict__ Qh, const half_t* __restrict__ Kh,
                     half_t* __restrict__ Sh, float2* __restrict__ part) {
  __shared__ half_t sA[128 * 32];
  __shared__ half_t sB[128 * 32];
  __shared__ float lm[2][128], ls[2][128];
  const int t = threadIdx.x;
  const int bz = blockIdx.z;
  const half_t* A = Qh + (size_t)bz * SEQ * HID;
  const half_t* B = Kh + (size_t)bz * SEQ * HID;
  half_t* Shb = Sh + (size_t)bz * SEQ * SEQ;
  const int m0 = blockIdx.y * 128;
  const int n0 = blockIdx.x * 128;
  const int lane = t & 63, wid = t >> 6;
  const int wr = (wid >> 1) * 64, wc = (wid & 1) * 64;
  const int lrow = lane & 15, lks = lane >> 4;
  const int s1 = t, s2 = t + 256;
  const int ar1 = s1 >> 2, ac1 = (s1 & 3) * 8;
  const int ar2 = s2 >> 2, ac2 = (s2 & 3) * 8;

  f32x4 acc[4][4] = {};

  for (int k0 = 0; k0 < HID; k0 += 32) {
    __syncthreads();
    GLOAD_LDS16(A + (size_t)(m0 + ar1) * HID + k0 + ac1, &sA[s1 * 8]);
    GLOAD_LDS16(A + (size_t)(m0 + ar2) * HID + k0 + ac2, &sA[s2 * 8]);
    GLOAD_LDS16(B + (size_t)(n0 + ar1) * HID + k0 + ac1, &sB[s1 * 8]);
    GLOAD_LDS16(B + (size_t)(n0 + ar2) * HID + k0 + ac2, &sB[s2 * 8]);
    __syncthreads();
    half8 a[4], b[4];
#pragma unroll
    for (int m = 0; m < 4; ++m)
      a[m] = *reinterpret_cast<const half8*>(&sA[(wr + m * 16 + lrow) * 32 + lks * 8]);
#pragma unroll
    for (int n = 0; n < 4; ++n)
      b[n] = *reinterpret_cast<const half8*>(&sB[(wc + n * 16 + lrow) * 32 + lks * 8]);
#pragma unroll
    for (int m = 0; m < 4; ++m)
#pragma unroll
      for (int n = 0; n < 4; ++n)
        acc[m][n] = __builtin_amdgcn_mfma_f32_16x16x32_f16(a[m], b[n], acc[m][n], 0, 0, 0);
  }

  // f16 raw-score write (row-major ws buffer, no aliasing with attn)
#pragma unroll
  for (int m = 0; m < 4; ++m)
#pragma unroll
    for (int n = 0; n < 4; ++n)
#pragma unroll
      for (int r = 0; r < 4; ++r)
        Shb[(size_t)(m0 + wr + m * 16 + lks * 4 + r) * SEQ +
            (n0 + wc + n * 16 + lrow)] = (half_t)acc[m][n][r];

  // per-tile softmax partials
#pragma unroll
  for (int m = 0; m < 4; ++m) {
#pragma unroll
    for (int r = 0; r < 4; ++r) {
      float mx = fmaxf(fmaxf(acc[m][0][r], acc[m][1][r]),
                       fmaxf(acc[m][2][r], acc[m][3][r]));
      mx = fmaxf(mx, __shfl_xor(mx, 1));
      mx = fmaxf(mx, __shfl_xor(mx, 2));
      mx = fmaxf(mx, __shfl_xor(mx, 4));
      mx = fmaxf(mx, __shfl_xor(mx, 8));
      float s = expf(acc[m][0][r] - mx) + expf(acc[m][1][r] - mx) +
                expf(acc[m][2][r] - mx) + expf(acc[m][3][r] - mx);
      s += __shfl_xor(s, 1);
      s += __shfl_xor(s, 2);
      s += __shfl_xor(s, 4);
      s += __shfl_xor(s, 8);
      if (lrow == 0) {
        const int rr = wr + m * 16 + lks * 4 + r;
        lm[wid & 1][rr] = mx;
        ls[wid & 1][rr] = s;
      }
    }
  }
  __syncthreads();
  if (t < 128) {
    const float m0v = lm[0][t], m1v = lm[1][t];
    const float M = fmaxf(m0v, m1v);
    const float L = ls[0][t] * expf(m0v - M) + ls[1][t] * expf(m1v - M);
    part[(size_t)(bz * SEQ + m0 + t) * 32 + blockIdx.x] = make_float2(M, L);
  }
}

// ---------------- merge 32 per-tile partials per row -> (rowmax, 1/rowsum) --------
__global__ void k_lred(const float2* __restrict__ part, float2* __restrict__ stats) {
  const int row = blockIdx.x * 256 + threadIdx.x;  // [0, NB*SEQ)
  const float2* p = part + (size_t)row * 32;
  float M = -3.4028235e38f;
#pragma unroll
  for (int i = 0; i < 32; ++i) M = fmaxf(M, p[i].x);
  float L = 0.f;
#pragma unroll
  for (int i = 0; i < 32; ++i) L += p[i].y * expf(p[i].x - M);
  stats[row] = make_float2(M, 1.0f / L);
}

// ---------------- fused PV at 32 waves/CU: read Sh -> exp -> attn + opt ----------
// BM=32, BN=256 (2 col-half blocks/row-block) -> 1024 blocks = 4/CU = 32 waves/CU.
// R9's proven pipeline: register Sh prefetch (prA/prB), deferred attn store
// (ch==0 blocks only), XOR-swizzled sA, lgkm-only barriers, Vf fragment loads.
// No aliasing: Sh read-only (ws), attn write-only.
__launch_bounds__(512, 8)
__global__ void k_pvw(const half_t* __restrict__ Sh, const half_t* __restrict__ Vf,
                      const float2* __restrict__ stats,
                      float* __restrict__ attn, float* __restrict__ O) {
  __shared__ half_t sA[2][32 * 128];  // 2 superchunk bufs, swizzled (16 KB)
  const int t = threadIdx.x;

  // bijective XCD swizzle; col-half pairs stay on one XCD
  const int bid = blockIdx.x;
  const int sw = (bid & 7) * 128 + (bid >> 3);
  const int rowblk = sw >> 1;       // 0..511
  const int ch = sw & 1;            // col half
  const int bz = rowblk >> 7;
  const int m0 = (rowblk & 127) * 32;

  const int lane = t & 63, wid = t >> 6;
  const int lrow = lane & 15, lks = lane >> 4;

  // per-thread Sh map: thread owns 8 keys (granule pc) of row prow per superchunk
  const int prow = t >> 4;          // 0..31
  const int pc = t & 15;            // granule (8 keys) within 128-key superchunk
  const float2 st = stats[(size_t)bz * SEQ + m0 + prow];
  const float m2p = st.x * LOG2E - __log2f(st.y);  // exp(s-M)*invl = 2^(s*l2e-m2p)

  const half_t* const Shrow =
      Sh + ((size_t)bz * SEQ + m0 + prow) * SEQ + pc * 8;
  float* const PArow =
      attn + (size_t)bz * SEQ * SEQ + (size_t)(m0 + prow) * SEQ + pc * 8;
  const int sidx = prow * 128 + ((pc ^ (prow & 15)) << 3);

  // a-frag swizzled read offsets: granule = (kc*4+lks) ^ (row&15)
  int aoff[2][4];
#pragma unroll
  for (int m = 0; m < 2; ++m)
#pragma unroll
    for (int kc = 0; kc < 4; ++kc) {
      const int row = m * 16 + lrow;
      aoff[m][kc] = row * 128 + (((kc * 4 + lks) ^ (row & 15)) << 3);
    }

  // V frag base: this wave covers cols [ch*256 + wid*32, +32) = hg {base, base+1}
  const half_t* const vb =
      Vf + ((size_t)bz * 4096 + ch * 16 + wid * 2) * 512 + lane * 8;

  f32x4 acc[2][2] = {};
  f32x4 e0, e1;
  half8 prA, prB;

#define PVW_EXPSTAGE(SB, PR)                                                 \
  {                                                                          \
    _Pragma("unroll")                                                        \
    for (int j = 0; j < 4; ++j) {                                            \
      e0[j] = exp2f((float)(PR)[j] * LOG2E - m2p);                           \
      e1[j] = exp2f((float)(PR)[j + 4] * LOG2E - m2p);                       \
    }                                                                        \
    half8 hv;                                                                \
    _Pragma("unroll")                                                        \
    for (int j = 0; j < 4; ++j) {                                            \
      hv[j] = (half_t)e0[j];                                                 \
      hv[j + 4] = (half_t)e1[j];                                             \
    }                                                                        \
    *reinterpret_cast<half8*>(&sA[SB][sidx]) = hv;                           \
  }

#define PVW_ITER(PRL, PRC, SC)                                               \
  {                                                                          \
    half8 b[8];                                                              \
    _Pragma("unroll")                                                        \
    for (int kc = 0; kc < 4; ++kc)                                           \
      _Pragma("unroll")                                                      \
      for (int n = 0; n < 2; ++n)                                            \
        b[kc * 2 + n] = *reinterpret_cast<const half8*>(                     \
            vb + ((size_t)((SC) * 4 + kc) * 32 + n) * 512);                  \
    if ((SC) + 2 < 32)                                                       \
      PRL = *reinterpret_cast<const half8*>(Shrow + ((SC) + 2) * 128);       \
    if (ch == 0) {                                                           \
      *reinterpret_cast<f32x4*>(PArow + (SC) * 128) = e0;                    \
      *reinterpret_cast<f32x4*>(PArow + (SC) * 128 + 4) = e1;                \
    }                                                                        \
    __builtin_amdgcn_sched_barrier(0);                                       \
    _Pragma("unroll")                                                        \
    for (int kc = 0; kc < 4; ++kc) {                                         \
      half8 a[2];                                                            \
      _Pragma("unroll")                                                      \
      for (int m = 0; m < 2; ++m)                                            \
        a[m] = *reinterpret_cast<const half8*>(&sA[(SC) & 1][aoff[m][kc]]);  \
      _Pragma("unroll")                                                      \
      for (int m = 0; m < 2; ++m)                                            \
        _Pragma("unroll")                                                    \
        for (int n = 0; n < 2; ++n)                                          \
          acc[m][n] = __builtin_amdgcn_mfma_f32_16x16x32_f16(                \
              a[m], b[kc * 2 + n], acc[m][n], 0, 0, 0);                      \
    }                                                                        \
    if ((SC) + 1 < 32) {                                                     \
      PVW_EXPSTAGE(((SC) + 1) & 1, PRC);                                     \
    }                                                                        \
    LGKM_BARRIER();                                                          \
  }

  // ---- prologue: consume Sh(0) -> sA[0]+e; prefetch Sh(1) ----
  {
    half8 pr0 = *reinterpret_cast<const half8*>(Shrow);
    PVW_EXPSTAGE(0, pr0);
    prB = *reinterpret_cast<const half8*>(Shrow + 128);
    LGKM_BARRIER();
  }

  for (int sc = 0; sc < 32; sc += 2) {
    PVW_ITER(prA, prB, sc);
    PVW_ITER(prB, prA, sc + 1);
  }

  float* const Ob = O + (size_t)bz * SEQ * HID;
#pragma unroll
  for (int m = 0; m < 2; ++m)
#pragma unroll
    for (int n = 0; n < 2; ++n)
#pragma unroll
      for (int r = 0; r < 4; ++r)
        Ob[(size_t)(m0 + m * 16 + lks * 4 + r) * HID + ch * 256 + wid * 32 +
           n * 16 + lrow] = acc[m][n][r];
}

extern "C" void kernel_launch(void* const* d_in, const int* in_sizes, int n_in,
                              void* d_out, int out_size, void* d_ws, size_t ws_size,
                              hipStream_t stream) {
  const float* x = (const float*)d_in[0];     // [4,4096,512]
  const float* W = (const float*)d_in[1];     // [512,1536]
  const float* bias = (const float*)d_in[2];  // [1536]
  float* opt = (float*)d_out;                        // [4*4096*512]
  float* attn = opt + (size_t)NB * SEQ * HID;        // [4*4096*4096]

  half_t* xh = (half_t*)d_ws;                        // 16.78 MB
  half_t* Wt = xh + (size_t)NB * SEQ * HID;          // 1.57 MB
  half_t* Qh = Wt + (size_t)N3 * HID;                // 16.78 MB
  half_t* Kh = Qh + (size_t)NB * SEQ * HID;          // 16.78 MB
  half_t* Vf = Kh + (size_t)NB * SEQ * HID;          // 16.78 MB (fragment-packed)
  float2* part = (float2*)(Vf + (size_t)NB * HID * SEQ);  // 4.19 MB
  float2* stats = part + (size_t)NB * SEQ * 32;           // 131 KB
  half_t* Sh = (half_t*)(stats + NB * SEQ);               // 134.2 MB (f16 scores)

  k_cvt<<<2048, 256, 0, stream>>>(x, xh, NB * SEQ * HID / 4);
  k_tw<<<dim3(N3 / 64, HID / 64), 256, 0, stream>>>(W, Wt);
  k_qkv<<<dim3(N3 / 128, NB * SEQ / 128), 256, 0, stream>>>(xh, Wt, bias, Qh, Kh, Vf);
  k_qk<<<dim3(SEQ / 128, SEQ / 128, NB), 256, 0, stream>>>(Qh, Kh, Sh, part);
  k_lred<<<NB * SEQ / 256, 256, 0, stream>>>(part, stats);
  k_pvw<<<1024, 512, 0, stream>>>(Sh, Vf, stats, attn, opt);
}